// Round 4
// baseline (586.690 us; speedup 1.0000x reference)
//
#include <hip/hip_runtime.h>
#include <hip/hip_bf16.h>
#include <stdint.h>

#define BB 32
#define LL 2048
#define DD 1024

typedef short short8  __attribute__((ext_vector_type(8)));
typedef float f32x4   __attribute__((ext_vector_type(4)));

__device__ __forceinline__ short f2bf(float f) {
    unsigned u = __float_as_uint(f);
    u += 0x7fffu + ((u >> 16) & 1u);      // round-to-nearest-even
    return (short)(u >> 16);
}

__device__ __forceinline__ float bf2f(unsigned short s) {
    return __uint_as_float(((unsigned)s) << 16);
}

__device__ __forceinline__ float fast_tanh(float x) {
    float e = __expf(2.f * x);
    return 1.f - 2.f * __builtin_amdgcn_rcpf(e + 1.f);
}

__device__ __forceinline__ void async_cp16(const void* g, void* l) {
    __builtin_amdgcn_global_load_lds(
        (__attribute__((address_space(1))) void*)g,
        (__attribute__((address_space(3))) void*)l, 16, 0, 0);
}

__device__ __forceinline__ short8 pack8(float4 a, float4 b) {
    short8 p;
    p[0] = f2bf(a.x); p[1] = f2bf(a.y); p[2] = f2bf(a.z); p[3] = f2bf(a.w);
    p[4] = f2bf(b.x); p[5] = f2bf(b.y); p[6] = f2bf(b.z); p[7] = f2bf(b.w);
    return p;
}

// ---------- fused prep: q' + U->bf16 + enc->bf16, one launch ----------
// blocks [0,512): q'[b][d] = Ww[d,:]·h[b,:] + Wb[d] + Ub[d]
// blocks [512,1024): U cvt ; blocks [1024, 33792): enc cvt
__global__ void prep_kernel(const float* __restrict__ dh, const float* __restrict__ Ww,
                            const float* __restrict__ Wb, const float* __restrict__ Ub,
                            const float* __restrict__ Uw, const float* __restrict__ enc,
                            float* __restrict__ qbuf, short* __restrict__ Ubf,
                            short* __restrict__ encbf) {
    const int bid = blockIdx.x, t = threadIdx.x;
    if (bid >= 512) {
        const float* src = (bid < 1024) ? Uw : enc;
        short* dst = (bid < 1024) ? Ubf : encbf;
        int base = (bid < 1024) ? (bid - 512) : (bid - 1024);
        size_t idx = ((size_t)base * 256 + t) * 8;
        float4 a = *(const float4*)(src + idx);
        float4 c = *(const float4*)(src + idx + 4);
        *(short8*)(dst + idx) = pack8(a, c);
        return;
    }
    int b  = bid >> 4;
    int d0 = (bid & 15) << 6;
    int w = t >> 6, lane = t & 63;
    __shared__ __align__(16) float hs[DD];
    *(float4*)&hs[t * 4] = *(const float4*)&dh[b * DD + t * 4];
    __syncthreads();
    float hr[16];
#pragma unroll
    for (int i = 0; i < 16; i++) hr[i] = hs[lane + 64 * i];
    for (int i = 0; i < 16; i++) {
        int d = d0 + w * 16 + i;
        const float* wr = Ww + (size_t)d * DD;
        float s = 0.f;
#pragma unroll
        for (int j = 0; j < 16; j++) s += wr[lane + 64 * j] * hr[j];
#pragma unroll
        for (int m = 1; m < 64; m <<= 1) s += __shfl_xor(s, m, 64);
        if (lane == 0) qbuf[b * DD + d] = s + Wb[d] + Ub[d];
    }
}

// ---------- Path A: bf16 GEMM, XCD-swizzled, double-buffered 2-phase prefetch ----------
// BK=32 per stage; while computing buf[cur], the next K-slab's global_load_lds
// are already in flight into buf[cur^1]. One __syncthreads per step (its
// implicit vmcnt(0) lands after the loads overlapped the whole compute phase).
__global__ __launch_bounds__(256, 4) void gemm_scores_bf(
    const short* __restrict__ encbf, const short* __restrict__ Ubf,
    const float* __restrict__ qbuf, const float* __restrict__ vw,
    float* __restrict__ spart) {
    __shared__ __align__(16) short As[2][128 * 32];
    __shared__ __align__(16) short Bs[2][128 * 32];
    __shared__ float q_s[128], v_s[128], s_acc[2][128];

    const int t = threadIdx.x;
    const int lane = t & 63, w = t >> 6;
    const int l15 = lane & 15, quad = lane >> 4;
    const int wm = w >> 1, wn = w & 1;

    // XCD swizzle: keep the 8 n-blocks of one m-stripe on ONE XCD so the
    // 256 KB A-stripe is fetched into a single L2.
    const int lin  = blockIdx.x + (blockIdx.y << 3);   // 0..4095
    const int xcd  = lin & 7;
    const int slot = lin >> 3;                          // 0..511
    const int nblk = slot & 7;
    const int mstripe = (xcd << 6) + (slot >> 3);       // 0..511
    const int n0 = nblk << 7;
    const int m0 = mstripe << 7;
    const int b  = m0 >> 11;

    if (t < 128) {
        q_s[t] = qbuf[(b << 10) + n0 + t];
        v_s[t] = vw[n0 + t];
    }

    f32x4 acc[4][4];
#pragma unroll
    for (int i = 0; i < 4; i++)
#pragma unroll
        for (int j = 0; j < 4; j++) acc[i][j] = (f32x4){0.f, 0.f, 0.f, 0.f};

    const int srow = lane >> 2, sseg = (lane & 3) << 3;
    const short* gA0 = encbf + (((size_t)(m0 + w * 32 + srow)) << 10) + sseg;
    const short* gB0 = Ubf   + (((size_t)(n0 + w * 32 + srow)) << 10) + sseg;
    const int lofs = w * 32 * 32;

    auto stage = [&](int buf, int k) {
        async_cp16(gA0 + k,              &As[buf][lofs]);
        async_cp16(gA0 + k + (16 << 10), &As[buf][lofs + 512]);
        async_cp16(gB0 + k,              &Bs[buf][lofs]);
        async_cp16(gB0 + k + (16 << 10), &Bs[buf][lofs + 512]);
    };
    auto compute = [&](int buf) {
        short8 af[4], bfv[4];
#pragma unroll
        for (int mt = 0; mt < 4; mt++)
            af[mt] = *(const short8*)&As[buf][(wm * 64 + mt * 16 + l15) * 32 + quad * 8];
#pragma unroll
        for (int nt = 0; nt < 4; nt++)
            bfv[nt] = *(const short8*)&Bs[buf][(wn * 64 + nt * 16 + l15) * 32 + quad * 8];
#pragma unroll
        for (int mt = 0; mt < 4; mt++)
#pragma unroll
            for (int nt = 0; nt < 4; nt++)
                acc[mt][nt] = __builtin_amdgcn_mfma_f32_16x16x32_bf16(
                    af[mt], bfv[nt], acc[mt][nt], 0, 0, 0);
    };

    // prologue: stage k=0 into buf 0
    stage(0, 0);
    __syncthreads();

    for (int it = 0; it < 16; ++it) {
        stage(1, (it << 6) + 32);     // prefetch next slab into buf1
        compute(0);                   // compute current slab (buf0)
        __syncthreads();              // drains prefetch vmcnt + protects reuse
        if (it < 15)
            stage(0, (it << 6) + 64); // prefetch into buf0
        compute(1);
        __syncthreads();
    }

    float qn[4], vn[4];
#pragma unroll
    for (int nt = 0; nt < 4; nt++) {
        qn[nt] = q_s[wn * 64 + nt * 16 + l15];
        vn[nt] = v_s[wn * 64 + nt * 16 + l15];
    }
#pragma unroll
    for (int mt = 0; mt < 4; mt++) {
#pragma unroll
        for (int r = 0; r < 4; r++) {
            float sum = 0.f;
#pragma unroll
            for (int nt = 0; nt < 4; nt++)
                sum += vn[nt] * fast_tanh(acc[mt][nt][r] + qn[nt]);
            sum += __shfl_xor(sum, 1, 64);
            sum += __shfl_xor(sum, 2, 64);
            sum += __shfl_xor(sum, 4, 64);
            sum += __shfl_xor(sum, 8, 64);
            if (l15 == 0)
                s_acc[wn][wm * 64 + mt * 16 + quad * 4 + r] = sum;
        }
    }
    __syncthreads();
    if (t < 128)
        spart[((size_t)nblk << 16) + m0 + t] = s_acc[0][t] + s_acc[1][t];
}

// ---------- Path A: 8-slab reduce + softmax (tiny, 32 blocks) ----------
__global__ void softmax8_kernel(const float* __restrict__ sp, float* __restrict__ attn) {
    const int b = blockIdx.x, t = threadIdx.x;   // 256 threads
    const int w = t >> 6, lane = t & 63;
    __shared__ float rm[4], rs[4];
    float v[8];
#pragma unroll
    for (int i = 0; i < 8; i++) {
        int l = t + (i << 8);
        float s = 0.f;
#pragma unroll
        for (int p = 0; p < 8; p++) s += sp[(p << 16) + (b << 11) + l];
        v[i] = s;
    }
    float m = v[0];
#pragma unroll
    for (int i = 1; i < 8; i++) m = fmaxf(m, v[i]);
#pragma unroll
    for (int s = 1; s < 64; s <<= 1) m = fmaxf(m, __shfl_xor(m, s, 64));
    if (lane == 0) rm[w] = m;
    __syncthreads();
    m = fmaxf(fmaxf(rm[0], rm[1]), fmaxf(rm[2], rm[3]));
    float s = 0.f;
#pragma unroll
    for (int i = 0; i < 8; i++) { v[i] = __expf(v[i] - m); s += v[i]; }
#pragma unroll
    for (int k = 1; k < 64; k <<= 1) s += __shfl_xor(s, k, 64);
    if (lane == 0) rs[w] = s;
    __syncthreads();
    s = rs[0] + rs[1] + rs[2] + rs[3];
    float inv = 1.f / s;
#pragma unroll
    for (int i = 0; i < 8; i++) attn[(b << 11) + t + (i << 8)] = v[i] * inv;
}

// ---------- Path A: context partials, high-occupancy (2048 blocks) ----------
__global__ void ctx_part(const short* __restrict__ encbf, const float* __restrict__ attn,
                         float* __restrict__ ctx) {
    const int dchunk = blockIdx.x;       // 0..7
    const int lslab  = blockIdx.y;       // 0..7
    const int b      = blockIdx.z;       // 0..31
    const int t = threadIdx.x;           // 0..255
    __shared__ float at_s[256];
    __shared__ float red[8][128];
    at_s[t] = attn[(b << 11) + (lslab << 8) + t];
    __syncthreads();
    const int d4 = (t & 31) << 2;
    const int dl = t >> 5;               // 0..7
    const int d0 = dchunk << 7;
    const short* base = encbf + ((size_t)b << 21) + ((size_t)lslab << 18) + d0 + d4;
    float ax = 0.f, ay = 0.f, az = 0.f, aw = 0.f;
#pragma unroll 8
    for (int i = 0; i < 32; i++) {
        int l = (i << 3) + dl;
        float wg = at_s[l];
        ushort4 e = *(const ushort4*)(base + ((size_t)l << 10));
        ax += wg * bf2f(e.x); ay += wg * bf2f(e.y);
        az += wg * bf2f(e.z); aw += wg * bf2f(e.w);
    }
    red[dl][d4 + 0] = ax;
    red[dl][d4 + 1] = ay;
    red[dl][d4 + 2] = az;
    red[dl][d4 + 3] = aw;
    __syncthreads();
    if (t < 128) {
        float s = 0.f;
#pragma unroll
        for (int j = 0; j < 8; j++) s += red[j][t];
        atomicAdd(&ctx[(b << 10) + d0 + t], s);
    }
}

// ---------- Path B fallback (small ws) ----------
__global__ void cvt_bf16_kernel(const float* __restrict__ src, short* __restrict__ dst) {
    int idx = (blockIdx.x * 256 + threadIdx.x) * 8;
    float4 a = *(const float4*)(src + idx);
    float4 c = *(const float4*)(src + idx + 4);
    *(short8*)(dst + idx) = pack8(a, c);
}

__global__ void q_kernel(const float* __restrict__ dh, const float* __restrict__ Ww,
                         const float* __restrict__ Wb, const float* __restrict__ Ub,
                         float* __restrict__ qbuf) {
    int b  = blockIdx.x >> 4;
    int d0 = (blockIdx.x & 15) << 6;
    int t = threadIdx.x, w = t >> 6, lane = t & 63;
    __shared__ __align__(16) float hs[DD];
    *(float4*)&hs[t * 4] = *(const float4*)&dh[b * DD + t * 4];
    __syncthreads();
    float hr[16];
#pragma unroll
    for (int i = 0; i < 16; i++) hr[i] = hs[lane + 64 * i];
    for (int i = 0; i < 16; i++) {
        int d = d0 + w * 16 + i;
        const float* wr = Ww + (size_t)d * DD;
        float s = 0.f;
#pragma unroll
        for (int j = 0; j < 16; j++) s += wr[lane + 64 * j] * hr[j];
#pragma unroll
        for (int m = 1; m < 64; m <<= 1) s += __shfl_xor(s, m, 64);
        if (lane == 0) qbuf[b * DD + d] = s + Wb[d] + Ub[d];
    }
}

__global__ __launch_bounds__(256, 3) void gemm_scores_f32(
    const float* __restrict__ enc, const short* __restrict__ Ubf,
    const float* __restrict__ qbuf, const float* __restrict__ vw,
    float* __restrict__ scores) {
    __shared__ __align__(16) short As[128 * 32];
    __shared__ __align__(16) short Bs[128 * 32];
    __shared__ float q_s[128], v_s[128], s_acc[128];

    const int t = threadIdx.x;
    const int lane = t & 63, w = t >> 6;
    const int l15 = lane & 15, quad = lane >> 4;
    const int wm = w >> 1, wn = w & 1;
    const int n0 = blockIdx.x << 7;
    const int m0 = blockIdx.y << 7;
    const int b  = m0 >> 11;

    if (t < 128) {
        q_s[t] = qbuf[(b << 10) + n0 + t];
        v_s[t] = vw[n0 + t];
        s_acc[t] = 0.f;
    }

    f32x4 acc[4][4];
#pragma unroll
    for (int i = 0; i < 4; i++)
#pragma unroll
        for (int j = 0; j < 4; j++) acc[i][j] = (f32x4){0.f, 0.f, 0.f, 0.f};

    const int arow = t >> 1, ahalf = t & 1;
    const float* aptr = enc + (((size_t)(m0 + arow)) << 10) + (ahalf << 4);
    short* adst = As + arow * 32 + ahalf * 16;
    const int brow = t >> 2, bks = (t & 3) * 8;
    const short* bptr1 = Ubf + ((size_t)(n0 + brow)) * 1024 + bks;
    const short* bptr2 = bptr1 + (size_t)64 * 1024;
    short* bdst1 = Bs + brow * 32 + bks;
    short* bdst2 = bdst1 + 64 * 32;

    for (int k0 = 0; k0 < 1024; k0 += 32) {
        __syncthreads();
        float4 f0 = *(const float4*)(aptr + k0);
        float4 f1 = *(const float4*)(aptr + k0 + 4);
        float4 f2 = *(const float4*)(aptr + k0 + 8);
        float4 f3 = *(const float4*)(aptr + k0 + 12);
        *(short8*)adst = pack8(f0, f1);
        *(short8*)(adst + 8) = pack8(f2, f3);
        *(short8*)bdst1 = *(const short8*)(bptr1 + k0);
        *(short8*)bdst2 = *(const short8*)(bptr2 + k0);
        __syncthreads();

        short8 af[4], bfv[4];
#pragma unroll
        for (int mt = 0; mt < 4; mt++)
            af[mt] = *(const short8*)&As[(wm * 64 + mt * 16 + l15) * 32 + quad * 8];
#pragma unroll
        for (int nt = 0; nt < 4; nt++)
            bfv[nt] = *(const short8*)&Bs[(wn * 64 + nt * 16 + l15) * 32 + quad * 8];
#pragma unroll
        for (int mt = 0; mt < 4; mt++)
#pragma unroll
            for (int nt = 0; nt < 4; nt++)
                acc[mt][nt] = __builtin_amdgcn_mfma_f32_16x16x32_bf16(
                    af[mt], bfv[nt], acc[mt][nt], 0, 0, 0);
    }

    float qn[4], vn[4];
#pragma unroll
    for (int nt = 0; nt < 4; nt++) {
        qn[nt] = q_s[wn * 64 + nt * 16 + l15];
        vn[nt] = v_s[wn * 64 + nt * 16 + l15];
    }
#pragma unroll
    for (int mt = 0; mt < 4; mt++) {
#pragma unroll
        for (int r = 0; r < 4; r++) {
            float sum = 0.f;
#pragma unroll
            for (int nt = 0; nt < 4; nt++)
                sum += vn[nt] * fast_tanh(acc[mt][nt][r] + qn[nt]);
            sum += __shfl_xor(sum, 1, 64);
            sum += __shfl_xor(sum, 2, 64);
            sum += __shfl_xor(sum, 4, 64);
            sum += __shfl_xor(sum, 8, 64);
            if (l15 == 0)
                atomicAdd(&s_acc[wm * 64 + mt * 16 + quad * 4 + r], sum);
        }
    }
    __syncthreads();
    if (t < 128) atomicAdd(&scores[m0 + t], s_acc[t]);
}

__global__ void softmax_kernel(const float* __restrict__ sp, float* __restrict__ attn) {
    int b = blockIdx.x, t = threadIdx.x;
    int w = t >> 6, lane = t & 63;
    __shared__ float rm[4], rs[4];
    float v[8];
#pragma unroll
    for (int i = 0; i < 8; i++) v[i] = sp[(b << 11) + t + (i << 8)];
    float m = v[0];
#pragma unroll
    for (int i = 1; i < 8; i++) m = fmaxf(m, v[i]);
#pragma unroll
    for (int s = 1; s < 64; s <<= 1) m = fmaxf(m, __shfl_xor(m, s, 64));
    if (lane == 0) rm[w] = m;
    __syncthreads();
    m = fmaxf(fmaxf(rm[0], rm[1]), fmaxf(rm[2], rm[3]));
    float s = 0.f;
#pragma unroll
    for (int i = 0; i < 8; i++) { v[i] = __expf(v[i] - m); s += v[i]; }
#pragma unroll
    for (int k = 1; k < 64; k <<= 1) s += __shfl_xor(s, k, 64);
    if (lane == 0) rs[w] = s;
    __syncthreads();
    s = rs[0] + rs[1] + rs[2] + rs[3];
    float inv = 1.f / s;
#pragma unroll
    for (int i = 0; i < 8; i++) attn[(b << 11) + t + (i << 8)] = v[i] * inv;
}

__global__ void context_f32(const float* __restrict__ enc, const float* __restrict__ attn,
                            float* __restrict__ ctx) {
    int dchunk = blockIdx.x, b = blockIdx.y;
    int t = threadIdx.x;
    __shared__ __align__(16) float at_s[2048];
    __shared__ float red[16][128];
    *(float4*)&at_s[t * 4] = *(const float4*)&attn[(b << 11) + t * 4];
    __syncthreads();
    int d4 = (t & 31) << 2;
    int dl = t >> 5;
    int d0 = dchunk << 7;
    const float* base = enc + ((size_t)b << 21) + d0 + d4;
    float ax = 0.f, ay = 0.f, az = 0.f, aw = 0.f;
#pragma unroll 4
    for (int i = 0; i < 128; i++) {
        int l = (i << 4) + dl;
        float wg = at_s[l];
        float4 e = *(const float4*)(base + ((size_t)l << 10));
        ax += wg * e.x; ay += wg * e.y; az += wg * e.z; aw += wg * e.w;
    }
    red[dl][d4 + 0] = ax;
    red[dl][d4 + 1] = ay;
    red[dl][d4 + 2] = az;
    red[dl][d4 + 3] = aw;
    __syncthreads();
    if (t < 128) {
        float s = 0.f;
#pragma unroll
        for (int j = 0; j < 16; j++) s += red[j][t];
        ctx[(b << 10) + d0 + t] = s;
    }
}

extern "C" void kernel_launch(void* const* d_in, const int* in_sizes, int n_in,
                              void* d_out, int out_size, void* d_ws, size_t ws_size,
                              hipStream_t stream) {
    const float* dh  = (const float*)d_in[0];
    const float* enc = (const float*)d_in[1];
    const float* Ww  = (const float*)d_in[2];
    const float* Wb  = (const float*)d_in[3];
    const float* Uw  = (const float*)d_in[4];
    const float* Ub  = (const float*)d_in[5];
    const float* vw  = (const float*)d_in[6];
    // d_in[7] = v_b: dropped (softmax shift-invariance)

    float* out  = (float*)d_out;               // [0,32768) context, [32768,98304) attn
    float* attn = out + BB * DD;
    char*  ws   = (char*)d_ws;
    short* Ubf   = (short*)ws;                           // 2 MB
    float* qbuf  = (float*)(ws + (2 << 20));             // 128 KB
    float* sbuf  = (float*)(ws + (2 << 20) + (1 << 17)); // 2 MB (8 slabs) / 256 KB (B)
    short* encbf = (short*)(ws + (8 << 20));             // 134.2 MB (Path A)

    bool bigws = ws_size >= ((size_t)143 << 20);

    if (bigws) {
        hipMemsetAsync(out, 0, (size_t)BB * DD * sizeof(float), stream);  // zero ctx for atomics
        prep_kernel<<<33792, 256, 0, stream>>>(dh, Ww, Wb, Ub, Uw, enc, qbuf, Ubf, encbf);
        gemm_scores_bf<<<dim3(8, 512), 256, 0, stream>>>(encbf, Ubf, qbuf, vw, sbuf);
        softmax8_kernel<<<BB, 256, 0, stream>>>(sbuf, attn);
        ctx_part<<<dim3(8, 8, BB), 256, 0, stream>>>(encbf, attn, out);
    } else {
        hipMemsetAsync(sbuf, 0, (size_t)BB * LL * sizeof(float), stream);
        cvt_bf16_kernel<<<512, 256, 0, stream>>>(Uw, Ubf);
        q_kernel<<<512, 256, 0, stream>>>(dh, Ww, Wb, Ub, qbuf);
        gemm_scores_f32<<<dim3(8, 512), 256, 0, stream>>>(enc, Ubf, qbuf, vw, sbuf);
        softmax_kernel<<<BB, 256, 0, stream>>>(sbuf, attn);
        context_f32<<<dim3(8, BB), 512, 0, stream>>>(enc, attn, out);
    }
}

// Round 6
// 584.686 us; speedup vs baseline: 1.0034x; 1.0034x over previous
//
#include <hip/hip_runtime.h>
#include <hip/hip_bf16.h>
#include <stdint.h>

#define BB 32
#define LL 2048
#define DD 1024

typedef short short8  __attribute__((ext_vector_type(8)));
typedef float f32x4   __attribute__((ext_vector_type(4)));

__device__ __forceinline__ short f2bf(float f) {
    unsigned u = __float_as_uint(f);
    u += 0x7fffu + ((u >> 16) & 1u);      // round-to-nearest-even
    return (short)(u >> 16);
}

__device__ __forceinline__ float bf2f(unsigned short s) {
    return __uint_as_float(((unsigned)s) << 16);
}

__device__ __forceinline__ float fast_tanh(float x) {
    float e = __expf(2.f * x);
    return 1.f - 2.f * __builtin_amdgcn_rcpf(e + 1.f);
}

__device__ __forceinline__ void async_cp16(const void* g, void* l) {
    __builtin_amdgcn_global_load_lds(
        (__attribute__((address_space(1))) void*)g,
        (__attribute__((address_space(3))) void*)l, 16, 0, 0);
}

__device__ __forceinline__ short8 pack8(float4 a, float4 b) {
    short8 p;
    p[0] = f2bf(a.x); p[1] = f2bf(a.y); p[2] = f2bf(a.z); p[3] = f2bf(a.w);
    p[4] = f2bf(b.x); p[5] = f2bf(b.y); p[6] = f2bf(b.z); p[7] = f2bf(b.w);
    return p;
}

// ---------- fused prep: q' + U->bf16 + enc->bf16, one launch ----------
__global__ void prep_kernel(const float* __restrict__ dh, const float* __restrict__ Ww,
                            const float* __restrict__ Wb, const float* __restrict__ Ub,
                            const float* __restrict__ Uw, const float* __restrict__ enc,
                            float* __restrict__ qbuf, short* __restrict__ Ubf,
                            short* __restrict__ encbf) {
    const int bid = blockIdx.x, t = threadIdx.x;
    if (bid >= 512) {
        const float* src = (bid < 1024) ? Uw : enc;
        short* dst = (bid < 1024) ? Ubf : encbf;
        int base = (bid < 1024) ? (bid - 512) : (bid - 1024);
        size_t idx = ((size_t)base * 256 + t) * 8;
        float4 a = *(const float4*)(src + idx);
        float4 c = *(const float4*)(src + idx + 4);
        *(short8*)(dst + idx) = pack8(a, c);
        return;
    }
    int b  = bid >> 4;
    int d0 = (bid & 15) << 6;
    int w = t >> 6, lane = t & 63;
    __shared__ __align__(16) float hs[DD];
    *(float4*)&hs[t * 4] = *(const float4*)&dh[b * DD + t * 4];
    __syncthreads();
    float hr[16];
#pragma unroll
    for (int i = 0; i < 16; i++) hr[i] = hs[lane + 64 * i];
    for (int i = 0; i < 16; i++) {
        int d = d0 + w * 16 + i;
        const float* wr = Ww + (size_t)d * DD;
        float s = 0.f;
#pragma unroll
        for (int j = 0; j < 16; j++) s += wr[lane + 64 * j] * hr[j];
#pragma unroll
        for (int m = 1; m < 64; m <<= 1) s += __shfl_xor(s, m, 64);
        if (lane == 0) qbuf[b * DD + d] = s + Wb[d] + Ub[d];
    }
}

// ---------- Path A: bf16 GEMM, XCD-swizzled, 3-slab ring pipeline ----------
// Phase j: ds_read slab j from buf[j%3] (XOR-swizzled, conflict-free),
// issue 4 global_load_lds for slab j+2 into buf[(j+2)%3], 16 MFMA,
// then s_waitcnt vmcnt(4) (slab j+1 landed, j+2 still flying) + s_barrier.
// Loads never drain to 0 in the main loop; in-flight window = 2 phases.
__global__ __launch_bounds__(256, 3) void gemm_scores_bf(
    const short* __restrict__ encbf, const short* __restrict__ Ubf,
    const float* __restrict__ qbuf, const float* __restrict__ vw,
    float* __restrict__ spart) {
    __shared__ __align__(16) short As[3 * 128 * 32];
    __shared__ __align__(16) short Bs[3 * 128 * 32];
    __shared__ float q_s[128], v_s[128], s_acc[2][128];

    const int t = threadIdx.x;
    const int lane = t & 63, w = t >> 6;
    const int l15 = lane & 15, quad = lane >> 4;
    const int wm = w >> 1, wn = w & 1;

    // XCD swizzle: keep the 8 n-blocks of one m-stripe on ONE XCD so the
    // 256 KB A-stripe is fetched into a single L2.
    const int lin  = blockIdx.x + (blockIdx.y << 3);   // 0..4095
    const int xcd  = lin & 7;
    const int slot = lin >> 3;                          // 0..511
    const int nblk = slot & 7;
    const int mstripe = (xcd << 6) + (slot >> 3);       // 0..511
    const int n0 = nblk << 7;
    const int m0 = mstripe << 7;
    const int b  = m0 >> 11;

    if (t < 128) {
        q_s[t] = qbuf[(b << 10) + n0 + t];
        v_s[t] = vw[n0 + t];
    }

    f32x4 acc[4][4];
#pragma unroll
    for (int i = 0; i < 4; i++)
#pragma unroll
        for (int j = 0; j < 4; j++) acc[i][j] = (f32x4){0.f, 0.f, 0.f, 0.f};

    // --- staging addresses: linear LDS dest, inverse-swizzled global source ---
    // LDS row r (64 B) holds global 16B-slot s at LDS slot s ^ ((r>>1)&3).
    // Staged rows per wave: r = 32w + (lane>>2) [+16] -> bits1-2 of r = bits1-2
    // of (lane>>2) -> source slot = (lane&3) ^ ((lane>>3)&3), per-lane constant.
    const int srow  = lane >> 2;
    const int sslot = ((lane & 3) ^ ((lane >> 3) & 3)) << 3;   // element offset
    const short* gA0 = encbf + (((size_t)(m0 + w * 32 + srow)) << 10) + sslot;
    const short* gB0 = Ubf   + (((size_t)(n0 + w * 32 + srow)) << 10) + sslot;
    const int lofs = w * 1024;                                  // wave-uniform LDS base
    // read-side swizzle: row bits1-2 come from l15 only
    const int qsw = (quad ^ ((l15 >> 1) & 3)) << 3;             // element offset

    auto stageSlab = [&](int buf, int k) {
        short* la = As + buf * 4096 + lofs;
        short* lb = Bs + buf * 4096 + lofs;
        async_cp16(gA0 + k,               la);
        async_cp16(gA0 + k + (16 << 10),  la + 512);
        async_cp16(gB0 + k,               lb);
        async_cp16(gB0 + k + (16 << 10),  lb + 512);
    };

    // prologue: slabs 0,1 in flight; wait for slab 0 (vmcnt 4 = slab 1 flying)
    stageSlab(0, 0);
    stageSlab(1, 32);
    asm volatile("s_waitcnt vmcnt(4)" ::: "memory");
    __builtin_amdgcn_s_barrier();
    __builtin_amdgcn_sched_barrier(0);

    int rb = 0, sb = 2;
    for (int j = 0; j < 32; ++j) {
        const short* Ab = As + rb * 4096;
        const short* Bb = Bs + rb * 4096;
        short8 af[4], bfv[4];
#pragma unroll
        for (int mt = 0; mt < 4; mt++)
            af[mt] = *(const short8*)&Ab[(wm * 64 + mt * 16 + l15) * 32 + qsw];
#pragma unroll
        for (int nt = 0; nt < 4; nt++)
            bfv[nt] = *(const short8*)&Bb[(wn * 64 + nt * 16 + l15) * 32 + qsw];
        if (j < 30) stageSlab(sb, (j + 2) << 5);
#pragma unroll
        for (int mt = 0; mt < 4; mt++)
#pragma unroll
            for (int nt = 0; nt < 4; nt++)
                acc[mt][nt] = __builtin_amdgcn_mfma_f32_16x16x32_bf16(
                    af[mt], bfv[nt], acc[mt][nt], 0, 0, 0);
        if (j < 31) {
            if (j < 30) asm volatile("s_waitcnt vmcnt(4)" ::: "memory");
            else        asm volatile("s_waitcnt vmcnt(0)" ::: "memory");
            __builtin_amdgcn_s_barrier();
            __builtin_amdgcn_sched_barrier(0);
        }
        rb = (rb == 2) ? 0 : rb + 1;
        sb = (sb == 2) ? 0 : sb + 1;
    }
    __syncthreads();

    float qn[4], vn[4];
#pragma unroll
    for (int nt = 0; nt < 4; nt++) {
        qn[nt] = q_s[wn * 64 + nt * 16 + l15];
        vn[nt] = v_s[wn * 64 + nt * 16 + l15];
    }
#pragma unroll
    for (int mt = 0; mt < 4; mt++) {
#pragma unroll
        for (int r = 0; r < 4; r++) {
            float sum = 0.f;
#pragma unroll
            for (int nt = 0; nt < 4; nt++)
                sum += vn[nt] * fast_tanh(acc[mt][nt][r] + qn[nt]);
            sum += __shfl_xor(sum, 1, 64);
            sum += __shfl_xor(sum, 2, 64);
            sum += __shfl_xor(sum, 4, 64);
            sum += __shfl_xor(sum, 8, 64);
            if (l15 == 0)
                s_acc[wn][wm * 64 + mt * 16 + quad * 4 + r] = sum;
        }
    }
    __syncthreads();
    if (t < 128)
        spart[((size_t)nblk << 16) + m0 + t] = s_acc[0][t] + s_acc[1][t];
}

// ---------- Path A: 8-slab reduce + softmax (tiny, 32 blocks) ----------
__global__ void softmax8_kernel(const float* __restrict__ sp, float* __restrict__ attn) {
    const int b = blockIdx.x, t = threadIdx.x;   // 256 threads
    const int w = t >> 6, lane = t & 63;
    __shared__ float rm[4], rs[4];
    float v[8];
#pragma unroll
    for (int i = 0; i < 8; i++) {
        int l = t + (i << 8);
        float s = 0.f;
#pragma unroll
        for (int p = 0; p < 8; p++) s += sp[(p << 16) + (b << 11) + l];
        v[i] = s;
    }
    float m = v[0];
#pragma unroll
    for (int i = 1; i < 8; i++) m = fmaxf(m, v[i]);
#pragma unroll
    for (int s = 1; s < 64; s <<= 1) m = fmaxf(m, __shfl_xor(m, s, 64));
    if (lane == 0) rm[w] = m;
    __syncthreads();
    m = fmaxf(fmaxf(rm[0], rm[1]), fmaxf(rm[2], rm[3]));
    float s = 0.f;
#pragma unroll
    for (int i = 0; i < 8; i++) { v[i] = __expf(v[i] - m); s += v[i]; }
#pragma unroll
    for (int k = 1; k < 64; k <<= 1) s += __shfl_xor(s, k, 64);
    if (lane == 0) rs[w] = s;
    __syncthreads();
    s = rs[0] + rs[1] + rs[2] + rs[3];
    float inv = 1.f / s;
#pragma unroll
    for (int i = 0; i < 8; i++) attn[(b << 11) + t + (i << 8)] = v[i] * inv;
}

// ---------- Path A: context partials, high-occupancy (2048 blocks) ----------
__global__ void ctx_part(const short* __restrict__ encbf, const float* __restrict__ attn,
                         float* __restrict__ ctx) {
    const int dchunk = blockIdx.x;       // 0..7
    const int lslab  = blockIdx.y;       // 0..7
    const int b      = blockIdx.z;       // 0..31
    const int t = threadIdx.x;           // 0..255
    __shared__ float at_s[256];
    __shared__ float red[8][128];
    at_s[t] = attn[(b << 11) + (lslab << 8) + t];
    __syncthreads();
    const int d4 = (t & 31) << 2;
    const int dl = t >> 5;               // 0..7
    const int d0 = dchunk << 7;
    const short* base = encbf + ((size_t)b << 21) + ((size_t)lslab << 18) + d0 + d4;
    float ax = 0.f, ay = 0.f, az = 0.f, aw = 0.f;
#pragma unroll 8
    for (int i = 0; i < 32; i++) {
        int l = (i << 3) + dl;
        float wg = at_s[l];
        ushort4 e = *(const ushort4*)(base + ((size_t)l << 10));
        ax += wg * bf2f(e.x); ay += wg * bf2f(e.y);
        az += wg * bf2f(e.z); aw += wg * bf2f(e.w);
    }
    red[dl][d4 + 0] = ax;
    red[dl][d4 + 1] = ay;
    red[dl][d4 + 2] = az;
    red[dl][d4 + 3] = aw;
    __syncthreads();
    if (t < 128) {
        float s = 0.f;
#pragma unroll
        for (int j = 0; j < 8; j++) s += red[j][t];
        atomicAdd(&ctx[(b << 10) + d0 + t], s);
    }
}

// ---------- Path B fallback (small ws) ----------
__global__ void cvt_bf16_kernel(const float* __restrict__ src, short* __restrict__ dst) {
    int idx = (blockIdx.x * 256 + threadIdx.x) * 8;
    float4 a = *(const float4*)(src + idx);
    float4 c = *(const float4*)(src + idx + 4);
    *(short8*)(dst + idx) = pack8(a, c);
}

__global__ void q_kernel(const float* __restrict__ dh, const float* __restrict__ Ww,
                         const float* __restrict__ Wb, const float* __restrict__ Ub,
                         float* __restrict__ qbuf) {
    int b  = blockIdx.x >> 4;
    int d0 = (blockIdx.x & 15) << 6;
    int t = threadIdx.x, w = t >> 6, lane = t & 63;
    __shared__ __align__(16) float hs[DD];
    *(float4*)&hs[t * 4] = *(const float4*)&dh[b * DD + t * 4];
    __syncthreads();
    float hr[16];
#pragma unroll
    for (int i = 0; i < 16; i++) hr[i] = hs[lane + 64 * i];
    for (int i = 0; i < 16; i++) {
        int d = d0 + w * 16 + i;
        const float* wr = Ww + (size_t)d * DD;
        float s = 0.f;
#pragma unroll
        for (int j = 0; j < 16; j++) s += wr[lane + 64 * j] * hr[j];
#pragma unroll
        for (int m = 1; m < 64; m <<= 1) s += __shfl_xor(s, m, 64);
        if (lane == 0) qbuf[b * DD + d] = s + Wb[d] + Ub[d];
    }
}

__global__ __launch_bounds__(256, 3) void gemm_scores_f32(
    const float* __restrict__ enc, const short* __restrict__ Ubf,
    const float* __restrict__ qbuf, const float* __restrict__ vw,
    float* __restrict__ scores) {
    __shared__ __align__(16) short As[128 * 32];
    __shared__ __align__(16) short Bs[128 * 32];
    __shared__ float q_s[128], v_s[128], s_acc[128];

    const int t = threadIdx.x;
    const int lane = t & 63, w = t >> 6;
    const int l15 = lane & 15, quad = lane >> 4;
    const int wm = w >> 1, wn = w & 1;
    const int n0 = blockIdx.x << 7;
    const int m0 = blockIdx.y << 7;
    const int b  = m0 >> 11;

    if (t < 128) {
        q_s[t] = qbuf[(b << 10) + n0 + t];
        v_s[t] = vw[n0 + t];
        s_acc[t] = 0.f;
    }

    f32x4 acc[4][4];
#pragma unroll
    for (int i = 0; i < 4; i++)
#pragma unroll
        for (int j = 0; j < 4; j++) acc[i][j] = (f32x4){0.f, 0.f, 0.f, 0.f};

    const int arow = t >> 1, ahalf = t & 1;
    const float* aptr = enc + (((size_t)(m0 + arow)) << 10) + (ahalf << 4);
    short* adst = As + arow * 32 + ahalf * 16;
    const int brow = t >> 2, bks = (t & 3) * 8;
    const short* bptr1 = Ubf + ((size_t)(n0 + brow)) * 1024 + bks;
    const short* bptr2 = bptr1 + (size_t)64 * 1024;
    short* bdst1 = Bs + brow * 32 + bks;
    short* bdst2 = bdst1 + 64 * 32;

    for (int k0 = 0; k0 < 1024; k0 += 32) {
        __syncthreads();
        float4 f0 = *(const float4*)(aptr + k0);
        float4 f1 = *(const float4*)(aptr + k0 + 4);
        float4 f2 = *(const float4*)(aptr + k0 + 8);
        float4 f3 = *(const float4*)(aptr + k0 + 12);
        *(short8*)adst = pack8(f0, f1);
        *(short8*)(adst + 8) = pack8(f2, f3);
        *(short8*)bdst1 = *(const short8*)(bptr1 + k0);
        *(short8*)bdst2 = *(const short8*)(bptr2 + k0);
        __syncthreads();

        short8 af[4], bfv[4];
#pragma unroll
        for (int mt = 0; mt < 4; mt++)
            af[mt] = *(const short8*)&As[(wm * 64 + mt * 16 + l15) * 32 + quad * 8];
#pragma unroll
        for (int nt = 0; nt < 4; nt++)
            bfv[nt] = *(const short8*)&Bs[(wn * 64 + nt * 16 + l15) * 32 + quad * 8];
#pragma unroll
        for (int mt = 0; mt < 4; mt++)
#pragma unroll
            for (int nt = 0; nt < 4; nt++)
                acc[mt][nt] = __builtin_amdgcn_mfma_f32_16x16x32_bf16(
                    af[mt], bfv[nt], acc[mt][nt], 0, 0, 0);
    }

    float qn[4], vn[4];
#pragma unroll
    for (int nt = 0; nt < 4; nt++) {
        qn[nt] = q_s[wn * 64 + nt * 16 + l15];
        vn[nt] = v_s[wn * 64 + nt * 16 + l15];
    }
#pragma unroll
    for (int mt = 0; mt < 4; mt++) {
#pragma unroll
        for (int r = 0; r < 4; r++) {
            float sum = 0.f;
#pragma unroll
            for (int nt = 0; nt < 4; nt++)
                sum += vn[nt] * fast_tanh(acc[mt][nt][r] + qn[nt]);
            sum += __shfl_xor(sum, 1, 64);
            sum += __shfl_xor(sum, 2, 64);
            sum += __shfl_xor(sum, 4, 64);
            sum += __shfl_xor(sum, 8, 64);
            if (l15 == 0)
                atomicAdd(&s_acc[wm * 64 + mt * 16 + quad * 4 + r], sum);
        }
    }
    __syncthreads();
    if (t < 128) atomicAdd(&scores[m0 + t], s_acc[t]);
}

__global__ void softmax_kernel(const float* __restrict__ sp, float* __restrict__ attn) {
    int b = blockIdx.x, t = threadIdx.x;
    int w = t >> 6, lane = t & 63;
    __shared__ float rm[4], rs[4];
    float v[8];
#pragma unroll
    for (int i = 0; i < 8; i++) v[i] = sp[(b << 11) + t + (i << 8)];
    float m = v[0];
#pragma unroll
    for (int i = 1; i < 8; i++) m = fmaxf(m, v[i]);
#pragma unroll
    for (int s = 1; s < 64; s <<= 1) m = fmaxf(m, __shfl_xor(m, s, 64));
    if (lane == 0) rm[w] = m;
    __syncthreads();
    m = fmaxf(fmaxf(rm[0], rm[1]), fmaxf(rm[2], rm[3]));
    float s = 0.f;
#pragma unroll
    for (int i = 0; i < 8; i++) { v[i] = __expf(v[i] - m); s += v[i]; }
#pragma unroll
    for (int k = 1; k < 64; k <<= 1) s += __shfl_xor(s, k, 64);
    if (lane == 0) rs[w] = s;
    __syncthreads();
    s = rs[0] + rs[1] + rs[2] + rs[3];
    float inv = 1.f / s;
#pragma unroll
    for (int i = 0; i < 8; i++) attn[(b << 11) + t + (i << 8)] = v[i] * inv;
}

__global__ void context_f32(const float* __restrict__ enc, const float* __restrict__ attn,
                            float* __restrict__ ctx) {
    int dchunk = blockIdx.x, b = blockIdx.y;
    int t = threadIdx.x;
    __shared__ __align__(16) float at_s[2048];
    __shared__ float red[16][128];
    *(float4*)&at_s[t * 4] = *(const float4*)&attn[(b << 11) + t * 4];
    __syncthreads();
    int d4 = (t & 31) << 2;
    int dl = t >> 5;
    int d0 = dchunk << 7;
    const float* base = enc + ((size_t)b << 21) + d0 + d4;
    float ax = 0.f, ay = 0.f, az = 0.f, aw = 0.f;
#pragma unroll 4
    for (int i = 0; i < 128; i++) {
        int l = (i << 4) + dl;
        float wg = at_s[l];
        float4 e = *(const float4*)(base + ((size_t)l << 10));
        ax += wg * e.x; ay += wg * e.y; az += wg * e.z; aw += wg * e.w;
    }
    red[dl][d4 + 0] = ax;
    red[dl][d4 + 1] = ay;
    red[dl][d4 + 2] = az;
    red[dl][d4 + 3] = aw;
    __syncthreads();
    if (t < 128) {
        float s = 0.f;
#pragma unroll
        for (int j = 0; j < 16; j++) s += red[j][t];
        ctx[(b << 10) + d0 + t] = s;
    }
}

extern "C" void kernel_launch(void* const* d_in, const int* in_sizes, int n_in,
                              void* d_out, int out_size, void* d_ws, size_t ws_size,
                              hipStream_t stream) {
    const float* dh  = (const float*)d_in[0];
    const float* enc = (const float*)d_in[1];
    const float* Ww  = (const float*)d_in[2];
    const float* Wb  = (const float*)d_in[3];
    const float* Uw  = (const float*)d_in[4];
    const float* Ub  = (const float*)d_in[5];
    const float* vw  = (const float*)d_in[6];
    // d_in[7] = v_b: dropped (softmax shift-invariance)

    float* out  = (float*)d_out;               // [0,32768) context, [32768,98304) attn
    float* attn = out + BB * DD;
    char*  ws   = (char*)d_ws;
    short* Ubf   = (short*)ws;                           // 2 MB
    float* qbuf  = (float*)(ws + (2 << 20));             // 128 KB
    float* sbuf  = (float*)(ws + (2 << 20) + (1 << 17)); // 2 MB (8 slabs) / 256 KB (B)
    short* encbf = (short*)(ws + (8 << 20));             // 134.2 MB (Path A)

    bool bigws = ws_size >= ((size_t)143 << 20);

    if (bigws) {
        hipMemsetAsync(out, 0, (size_t)BB * DD * sizeof(float), stream);  // zero ctx for atomics
        prep_kernel<<<33792, 256, 0, stream>>>(dh, Ww, Wb, Ub, Uw, enc, qbuf, Ubf, encbf);
        gemm_scores_bf<<<dim3(8, 512), 256, 0, stream>>>(encbf, Ubf, qbuf, vw, sbuf);
        softmax8_kernel<<<BB, 256, 0, stream>>>(sbuf, attn);
        ctx_part<<<dim3(8, 8, BB), 256, 0, stream>>>(encbf, attn, out);
    } else {
        hipMemsetAsync(sbuf, 0, (size_t)BB * LL * sizeof(float), stream);
        cvt_bf16_kernel<<<512, 256, 0, stream>>>(Uw, Ubf);
        q_kernel<<<512, 256, 0, stream>>>(dh, Ww, Wb, Ub, qbuf);
        gemm_scores_f32<<<dim3(8, 512), 256, 0, stream>>>(enc, Ubf, qbuf, vw, sbuf);
        softmax_kernel<<<BB, 256, 0, stream>>>(sbuf, attn);
        context_f32<<<dim3(8, BB), 512, 0, stream>>>(enc, attn, out);
    }
}

// Round 7
// 578.372 us; speedup vs baseline: 1.0144x; 1.0109x over previous
//
#include <hip/hip_runtime.h>
#include <hip/hip_bf16.h>
#include <stdint.h>

#define BB 32
#define LL 2048
#define DD 1024

typedef short short8  __attribute__((ext_vector_type(8)));
typedef float f32x4   __attribute__((ext_vector_type(4)));

__device__ __forceinline__ short f2bf(float f) {
    unsigned u = __float_as_uint(f);
    u += 0x7fffu + ((u >> 16) & 1u);      // round-to-nearest-even
    return (short)(u >> 16);
}

__device__ __forceinline__ float bf2f(unsigned short s) {
    return __uint_as_float(((unsigned)s) << 16);
}

__device__ __forceinline__ float fast_tanh(float x) {
    float e = __expf(2.f * x);
    return 1.f - 2.f * __builtin_amdgcn_rcpf(e + 1.f);
}

__device__ __forceinline__ void async_cp16(const void* g, void* l) {
    __builtin_amdgcn_global_load_lds(
        (__attribute__((address_space(1))) void*)g,
        (__attribute__((address_space(3))) void*)l, 16, 0, 0);
}

__device__ __forceinline__ short8 pack8(float4 a, float4 b) {
    short8 p;
    p[0] = f2bf(a.x); p[1] = f2bf(a.y); p[2] = f2bf(a.z); p[3] = f2bf(a.w);
    p[4] = f2bf(b.x); p[5] = f2bf(b.y); p[6] = f2bf(b.z); p[7] = f2bf(b.w);
    return p;
}

// ---------- fused prep: q' + U->bf16 + enc->bf16, one launch ----------
__global__ void prep_kernel(const float* __restrict__ dh, const float* __restrict__ Ww,
                            const float* __restrict__ Wb, const float* __restrict__ Ub,
                            const float* __restrict__ Uw, const float* __restrict__ enc,
                            float* __restrict__ qbuf, short* __restrict__ Ubf,
                            short* __restrict__ encbf) {
    const int bid = blockIdx.x, t = threadIdx.x;
    if (bid >= 512) {
        const float* src = (bid < 1024) ? Uw : enc;
        short* dst = (bid < 1024) ? Ubf : encbf;
        int base = (bid < 1024) ? (bid - 512) : (bid - 1024);
        size_t idx = ((size_t)base * 256 + t) * 8;
        float4 a = *(const float4*)(src + idx);
        float4 c = *(const float4*)(src + idx + 4);
        *(short8*)(dst + idx) = pack8(a, c);
        return;
    }
    int b  = bid >> 4;
    int d0 = (bid & 15) << 6;
    int w = t >> 6, lane = t & 63;
    __shared__ __align__(16) float hs[DD];
    *(float4*)&hs[t * 4] = *(const float4*)&dh[b * DD + t * 4];
    __syncthreads();
    float hr[16];
#pragma unroll
    for (int i = 0; i < 16; i++) hr[i] = hs[lane + 64 * i];
    for (int i = 0; i < 16; i++) {
        int d = d0 + w * 16 + i;
        const float* wr = Ww + (size_t)d * DD;
        float s = 0.f;
#pragma unroll
        for (int j = 0; j < 16; j++) s += wr[lane + 64 * j] * hr[j];
#pragma unroll
        for (int m = 1; m < 64; m <<= 1) s += __shfl_xor(s, m, 64);
        if (lane == 0) qbuf[b * DD + d] = s + Wb[d] + Ub[d];
    }
}

// ---------- Path A: 256x256 8-wave phased GEMM (BK=64, single-set freed-region restage) ----------
// 4 phases per K-tile; each: {ds_read subtile | stage freed rounds of next tile |
// 16 MFMA (setprio-wrapped) | raw barrier}. Counted vmcnt(2) at p2/p4 (never 0
// in steady state). T2 XOR swizzle: LDS(row, slot) = global(row, slot ^ (row&7)).
__global__ __launch_bounds__(512, 2) void gemm_scores_bf(
    const short* __restrict__ encbf, const short* __restrict__ Ubf,
    const float* __restrict__ qbuf, const float* __restrict__ vw,
    float* __restrict__ spart) {
    __shared__ __align__(16) short As[256 * 64];   // 32 KB, one K-tile of A
    __shared__ __align__(16) short Bs[256 * 64];   // 32 KB, one K-tile of B
    __shared__ float q_s[256], v_s[256];
    __shared__ float s_acc[4][256];

    const int t = threadIdx.x;            // 0..511
    const int lane = t & 63, wid = t >> 6;
    const int l15 = lane & 15, quad = lane >> 4;
    const int wm = wid >> 2, wn = wid & 3;   // 2M x 4N waves

    // XCD swizzle: 4 n-blocks of one m-stripe on one XCD (A-stripe 512 KB -> one L2)
    const int lin  = blockIdx.x + (blockIdx.y << 2);   // 0..1023
    const int xcd  = lin & 7;
    const int slot = lin >> 3;                          // 0..127
    const int nblk = slot & 3;
    const int mstripe = (xcd << 5) + (slot >> 2);       // 0..255
    const int n0 = nblk << 8;
    const int m0 = mstripe << 8;
    const int b  = m0 >> 11;

    if (t < 256) {
        q_s[t] = qbuf[(b << 10) + n0 + t];
        v_s[t] = vw[n0 + t];
    }

    f32x4 acc[8][4];
#pragma unroll
    for (int i = 0; i < 8; i++)
#pragma unroll
        for (int j = 0; j < 4; j++) acc[i][j] = (f32x4){0.f, 0.f, 0.f, 0.f};

    // staging: thread t covers row (t>>3) of each 64-row round, 16B seg (t&7),
    // global seg pre-swizzled so linear gload_lds dest yields swizzled LDS.
    const int grow = t >> 3;                                   // 0..63
    const int gseg = ((t & 7) ^ ((t >> 3) & 7)) << 3;          // element offset
    const short* gA = encbf + (((size_t)(m0 + grow)) << 10) + gseg;
    const short* gB = Ubf   + (((size_t)(n0 + grow)) << 10) + gseg;
    short* const lA = As + (wid << 9);                          // wave-uniform base
    short* const lB = Bs + (wid << 9);

    // read-side swizzle: slot = ks*4+quad, XOR row&7 (= l15&7)
    const int swz0 = ((quad)     ^ (l15 & 7)) << 3;
    const int swz1 = ((4 + quad) ^ (l15 & 7)) << 3;
    const int arow = (((wm << 7) + l15)) << 6;   // (wm*128+l15)*64 elements
    const int brow = (((wn << 6) + l15)) << 6;   // (wn*64+l15)*64

#define STA(i, k0) async_cp16(gA + ((size_t)(i) << 16) + (k0), lA + ((i) << 12))
#define STB(i, k0) async_cp16(gB + ((size_t)(i) << 16) + (k0), lB + ((i) << 12))

    // prologue: stage tile 0 fully, drain once
    STA(0, 0); STA(1, 0); STA(2, 0); STA(3, 0);
    STB(0, 0); STB(1, 0); STB(2, 0); STB(3, 0);
    asm volatile("s_waitcnt vmcnt(0)" ::: "memory");
    __builtin_amdgcn_s_barrier();
    __builtin_amdgcn_sched_barrier(0);

    short8 a_[4][2], b0_[2][2], b1_[2][2];

    for (int kt = 0; kt < 16; ++kt) {
        const int k1 = (kt + 1) << 6;
        const bool st = kt < 15;

        // ---- p1: read a(mh0: rounds 0,2) + b0(nh0); MFMA q(0,0)
#pragma unroll
        for (int m = 0; m < 4; m++) {
            a_[m][0] = *(const short8*)&As[arow + (m << 10) + swz0];
            a_[m][1] = *(const short8*)&As[arow + (m << 10) + swz1];
        }
#pragma unroll
        for (int n = 0; n < 2; n++) {
            b0_[n][0] = *(const short8*)&Bs[brow + (n << 10) + swz0];
            b0_[n][1] = *(const short8*)&Bs[brow + (n << 10) + swz1];
        }
        asm volatile("s_waitcnt lgkmcnt(0)" ::: "memory");
        __builtin_amdgcn_sched_barrier(0);
        __builtin_amdgcn_s_setprio(1);
#pragma unroll
        for (int m = 0; m < 4; m++)
#pragma unroll
            for (int n = 0; n < 2; n++) {
                acc[m][n] = __builtin_amdgcn_mfma_f32_16x16x32_bf16(a_[m][0], b0_[n][0], acc[m][n], 0, 0, 0);
                acc[m][n] = __builtin_amdgcn_mfma_f32_16x16x32_bf16(a_[m][1], b0_[n][1], acc[m][n], 0, 0, 0);
            }
        __builtin_amdgcn_s_setprio(0);
        __builtin_amdgcn_s_barrier();
        __builtin_amdgcn_sched_barrier(0);

        // ---- p2: read b1(nh1); stage A rounds 0,2 (freed by p1); MFMA q(0,1)
#pragma unroll
        for (int n = 0; n < 2; n++) {
            b1_[n][0] = *(const short8*)&Bs[brow + ((n + 2) << 10) + swz0];
            b1_[n][1] = *(const short8*)&Bs[brow + ((n + 2) << 10) + swz1];
        }
        if (st) { STA(0, k1); STA(2, k1); }
        asm volatile("s_waitcnt lgkmcnt(0)" ::: "memory");
        __builtin_amdgcn_sched_barrier(0);
        __builtin_amdgcn_s_setprio(1);
#pragma unroll
        for (int m = 0; m < 4; m++)
#pragma unroll
            for (int n = 0; n < 2; n++) {
                acc[m][n + 2] = __builtin_amdgcn_mfma_f32_16x16x32_bf16(a_[m][0], b1_[n][0], acc[m][n + 2], 0, 0, 0);
                acc[m][n + 2] = __builtin_amdgcn_mfma_f32_16x16x32_bf16(a_[m][1], b1_[n][1], acc[m][n + 2], 0, 0, 0);
            }
        __builtin_amdgcn_s_setprio(0);
        if (st) asm volatile("s_waitcnt vmcnt(2)" ::: "memory");   // prev p4's A(1,3) landed
        else    asm volatile("s_waitcnt vmcnt(0)" ::: "memory");
        __builtin_amdgcn_s_barrier();
        __builtin_amdgcn_sched_barrier(0);

        // ---- p3: read a(mh1: rounds 1,3); stage all B (freed by p1/p2); MFMA q(1,1)
#pragma unroll
        for (int m = 0; m < 4; m++) {
            a_[m][0] = *(const short8*)&As[arow + ((m + 4) << 10) + swz0];
            a_[m][1] = *(const short8*)&As[arow + ((m + 4) << 10) + swz1];
        }
        if (st) { STB(0, k1); STB(1, k1); STB(2, k1); STB(3, k1); }
        asm volatile("s_waitcnt lgkmcnt(0)" ::: "memory");
        __builtin_amdgcn_sched_barrier(0);
        __builtin_amdgcn_s_setprio(1);
#pragma unroll
        for (int m = 0; m < 4; m++)
#pragma unroll
            for (int n = 0; n < 2; n++) {
                acc[m + 4][n + 2] = __builtin_amdgcn_mfma_f32_16x16x32_bf16(a_[m][0], b1_[n][0], acc[m + 4][n + 2], 0, 0, 0);
                acc[m + 4][n + 2] = __builtin_amdgcn_mfma_f32_16x16x32_bf16(a_[m][1], b1_[n][1], acc[m + 4][n + 2], 0, 0, 0);
            }
        __builtin_amdgcn_s_setprio(0);
        __builtin_amdgcn_s_barrier();
        __builtin_amdgcn_sched_barrier(0);

        // ---- p4: stage A rounds 1,3 (freed by p3); MFMA q(1,0) (b0 still in regs)
        if (st) { STA(1, k1); STA(3, k1); }
        __builtin_amdgcn_s_setprio(1);
#pragma unroll
        for (int m = 0; m < 4; m++)
#pragma unroll
            for (int n = 0; n < 2; n++) {
                acc[m + 4][n] = __builtin_amdgcn_mfma_f32_16x16x32_bf16(a_[m][0], b0_[n][0], acc[m + 4][n], 0, 0, 0);
                acc[m + 4][n] = __builtin_amdgcn_mfma_f32_16x16x32_bf16(a_[m][1], b0_[n][1], acc[m + 4][n], 0, 0, 0);
            }
        __builtin_amdgcn_s_setprio(0);
        if (st) asm volatile("s_waitcnt vmcnt(2)" ::: "memory");   // A(0,2)+B landed; p4's 2 fly
        else    asm volatile("s_waitcnt vmcnt(0)" ::: "memory");
        __builtin_amdgcn_s_barrier();
        __builtin_amdgcn_sched_barrier(0);
    }
#undef STA
#undef STB

    // epilogue: scores partial over this block's 256-col slab
    float qn[4], vn[4];
#pragma unroll
    for (int nt = 0; nt < 4; nt++) {
        qn[nt] = q_s[(wn << 6) + nt * 16 + l15];
        vn[nt] = v_s[(wn << 6) + nt * 16 + l15];
    }
#pragma unroll
    for (int mt = 0; mt < 8; mt++) {
#pragma unroll
        for (int r = 0; r < 4; r++) {
            float sum = 0.f;
#pragma unroll
            for (int nt = 0; nt < 4; nt++)
                sum += vn[nt] * fast_tanh(acc[mt][nt][r] + qn[nt]);
            sum += __shfl_xor(sum, 1, 64);
            sum += __shfl_xor(sum, 2, 64);
            sum += __shfl_xor(sum, 4, 64);
            sum += __shfl_xor(sum, 8, 64);
            if (l15 == 0)
                s_acc[wn][(wm << 7) + mt * 16 + (quad << 2) + r] = sum;
        }
    }
    __syncthreads();
    if (t < 256)
        spart[((size_t)nblk << 16) + m0 + t] =
            s_acc[0][t] + s_acc[1][t] + s_acc[2][t] + s_acc[3][t];
}

// ---------- Path A: 4-slab reduce + softmax (tiny, 32 blocks) ----------
__global__ void softmax8_kernel(const float* __restrict__ sp, float* __restrict__ attn) {
    const int b = blockIdx.x, t = threadIdx.x;   // 256 threads
    const int w = t >> 6, lane = t & 63;
    __shared__ float rm[4], rs[4];
    float v[8];
#pragma unroll
    for (int i = 0; i < 8; i++) {
        int l = t + (i << 8);
        float s = 0.f;
#pragma unroll
        for (int p = 0; p < 4; p++) s += sp[(p << 16) + (b << 11) + l];
        v[i] = s;
    }
    float m = v[0];
#pragma unroll
    for (int i = 1; i < 8; i++) m = fmaxf(m, v[i]);
#pragma unroll
    for (int s = 1; s < 64; s <<= 1) m = fmaxf(m, __shfl_xor(m, s, 64));
    if (lane == 0) rm[w] = m;
    __syncthreads();
    m = fmaxf(fmaxf(rm[0], rm[1]), fmaxf(rm[2], rm[3]));
    float s = 0.f;
#pragma unroll
    for (int i = 0; i < 8; i++) { v[i] = __expf(v[i] - m); s += v[i]; }
#pragma unroll
    for (int k = 1; k < 64; k <<= 1) s += __shfl_xor(s, k, 64);
    if (lane == 0) rs[w] = s;
    __syncthreads();
    s = rs[0] + rs[1] + rs[2] + rs[3];
    float inv = 1.f / s;
#pragma unroll
    for (int i = 0; i < 8; i++) attn[(b << 11) + t + (i << 8)] = v[i] * inv;
}

// ---------- Path A: context partials, high-occupancy (2048 blocks) ----------
__global__ void ctx_part(const short* __restrict__ encbf, const float* __restrict__ attn,
                         float* __restrict__ ctx) {
    const int dchunk = blockIdx.x;       // 0..7
    const int lslab  = blockIdx.y;       // 0..7
    const int b      = blockIdx.z;       // 0..31
    const int t = threadIdx.x;           // 0..255
    __shared__ float at_s[256];
    __shared__ float red[8][128];
    at_s[t] = attn[(b << 11) + (lslab << 8) + t];
    __syncthreads();
    const int d4 = (t & 31) << 2;
    const int dl = t >> 5;               // 0..7
    const int d0 = dchunk << 7;
    const short* base = encbf + ((size_t)b << 21) + ((size_t)lslab << 18) + d0 + d4;
    float ax = 0.f, ay = 0.f, az = 0.f, aw = 0.f;
#pragma unroll 8
    for (int i = 0; i < 32; i++) {
        int l = (i << 3) + dl;
        float wg = at_s[l];
        ushort4 e = *(const ushort4*)(base + ((size_t)l << 10));
        ax += wg * bf2f(e.x); ay += wg * bf2f(e.y);
        az += wg * bf2f(e.z); aw += wg * bf2f(e.w);
    }
    red[dl][d4 + 0] = ax;
    red[dl][d4 + 1] = ay;
    red[dl][d4 + 2] = az;
    red[dl][d4 + 3] = aw;
    __syncthreads();
    if (t < 128) {
        float s = 0.f;
#pragma unroll
        for (int j = 0; j < 8; j++) s += red[j][t];
        atomicAdd(&ctx[(b << 10) + d0 + t], s);
    }
}

// ---------- Path B fallback (small ws) ----------
__global__ void cvt_bf16_kernel(const float* __restrict__ src, short* __restrict__ dst) {
    int idx = (blockIdx.x * 256 + threadIdx.x) * 8;
    float4 a = *(const float4*)(src + idx);
    float4 c = *(const float4*)(src + idx + 4);
    *(short8*)(dst + idx) = pack8(a, c);
}

__global__ void q_kernel(const float* __restrict__ dh, const float* __restrict__ Ww,
                         const float* __restrict__ Wb, const float* __restrict__ Ub,
                         float* __restrict__ qbuf) {
    int b  = blockIdx.x >> 4;
    int d0 = (blockIdx.x & 15) << 6;
    int t = threadIdx.x, w = t >> 6, lane = t & 63;
    __shared__ __align__(16) float hs[DD];
    *(float4*)&hs[t * 4] = *(const float4*)&dh[b * DD + t * 4];
    __syncthreads();
    float hr[16];
#pragma unroll
    for (int i = 0; i < 16; i++) hr[i] = hs[lane + 64 * i];
    for (int i = 0; i < 16; i++) {
        int d = d0 + w * 16 + i;
        const float* wr = Ww + (size_t)d * DD;
        float s = 0.f;
#pragma unroll
        for (int j = 0; j < 16; j++) s += wr[lane + 64 * j] * hr[j];
#pragma unroll
        for (int m = 1; m < 64; m <<= 1) s += __shfl_xor(s, m, 64);
        if (lane == 0) qbuf[b * DD + d] = s + Wb[d] + Ub[d];
    }
}

__global__ __launch_bounds__(256, 3) void gemm_scores_f32(
    const float* __restrict__ enc, const short* __restrict__ Ubf,
    const float* __restrict__ qbuf, const float* __restrict__ vw,
    float* __restrict__ scores) {
    __shared__ __align__(16) short As[128 * 32];
    __shared__ __align__(16) short Bs[128 * 32];
    __shared__ float q_s[128], v_s[128], s_acc[128];

    const int t = threadIdx.x;
    const int lane = t & 63, w = t >> 6;
    const int l15 = lane & 15, quad = lane >> 4;
    const int wm = w >> 1, wn = w & 1;
    const int n0 = blockIdx.x << 7;
    const int m0 = blockIdx.y << 7;
    const int b  = m0 >> 11;

    if (t < 128) {
        q_s[t] = qbuf[(b << 10) + n0 + t];
        v_s[t] = vw[n0 + t];
        s_acc[t] = 0.f;
    }

    f32x4 acc[4][4];
#pragma unroll
    for (int i = 0; i < 4; i++)
#pragma unroll
        for (int j = 0; j < 4; j++) acc[i][j] = (f32x4){0.f, 0.f, 0.f, 0.f};

    const int arow = t >> 1, ahalf = t & 1;
    const float* aptr = enc + (((size_t)(m0 + arow)) << 10) + (ahalf << 4);
    short* adst = As + arow * 32 + ahalf * 16;
    const int brow = t >> 2, bks = (t & 3) * 8;
    const short* bptr1 = Ubf + ((size_t)(n0 + brow)) * 1024 + bks;
    const short* bptr2 = bptr1 + (size_t)64 * 1024;
    short* bdst1 = Bs + brow * 32 + bks;
    short* bdst2 = bdst1 + 64 * 32;

    for (int k0 = 0; k0 < 1024; k0 += 32) {
        __syncthreads();
        float4 f0 = *(const float4*)(aptr + k0);
        float4 f1 = *(const float4*)(aptr + k0 + 4);
        float4 f2 = *(const float4*)(aptr + k0 + 8);
        float4 f3 = *(const float4*)(aptr + k0 + 12);
        *(short8*)adst = pack8(f0, f1);
        *(short8*)(adst + 8) = pack8(f2, f3);
        *(short8*)bdst1 = *(const short8*)(bptr1 + k0);
        *(short8*)bdst2 = *(const short8*)(bptr2 + k0);
        __syncthreads();

        short8 af[4], bfv[4];
#pragma unroll
        for (int mt = 0; mt < 4; mt++)
            af[mt] = *(const short8*)&As[(wm * 64 + mt * 16 + l15) * 32 + quad * 8];
#pragma unroll
        for (int nt = 0; nt < 4; nt++)
            bfv[nt] = *(const short8*)&Bs[(wn * 64 + nt * 16 + l15) * 32 + quad * 8];
#pragma unroll
        for (int mt = 0; mt < 4; mt++)
#pragma unroll
            for (int nt = 0; nt < 4; nt++)
                acc[mt][nt] = __builtin_amdgcn_mfma_f32_16x16x32_bf16(
                    af[mt], bfv[nt], acc[mt][nt], 0, 0, 0);
    }

    float qn[4], vn[4];
#pragma unroll
    for (int nt = 0; nt < 4; nt++) {
        qn[nt] = q_s[wn * 64 + nt * 16 + l15];
        vn[nt] = v_s[wn * 64 + nt * 16 + l15];
    }
#pragma unroll
    for (int mt = 0; mt < 4; mt++) {
#pragma unroll
        for (int r = 0; r < 4; r++) {
            float sum = 0.f;
#pragma unroll
            for (int nt = 0; nt < 4; nt++)
                sum += vn[nt] * fast_tanh(acc[mt][nt][r] + qn[nt]);
            sum += __shfl_xor(sum, 1, 64);
            sum += __shfl_xor(sum, 2, 64);
            sum += __shfl_xor(sum, 4, 64);
            sum += __shfl_xor(sum, 8, 64);
            if (l15 == 0)
                atomicAdd(&s_acc[wm * 64 + mt * 16 + quad * 4 + r], sum);
        }
    }
    __syncthreads();
    if (t < 128) atomicAdd(&scores[m0 + t], s_acc[t]);
}

__global__ void softmax_kernel(const float* __restrict__ sp, float* __restrict__ attn) {
    int b = blockIdx.x, t = threadIdx.x;
    int w = t >> 6, lane = t & 63;
    __shared__ float rm[4], rs[4];
    float v[8];
#pragma unroll
    for (int i = 0; i < 8; i++) v[i] = sp[(b << 11) + t + (i << 8)];
    float m = v[0];
#pragma unroll
    for (int i = 1; i < 8; i++) m = fmaxf(m, v[i]);
#pragma unroll
    for (int s = 1; s < 64; s <<= 1) m = fmaxf(m, __shfl_xor(m, s, 64));
    if (lane == 0) rm[w] = m;
    __syncthreads();
    m = fmaxf(fmaxf(rm[0], rm[1]), fmaxf(rm[2], rm[3]));
    float s = 0.f;
#pragma unroll
    for (int i = 0; i < 8; i++) { v[i] = __expf(v[i] - m); s += v[i]; }
#pragma unroll
    for (int k = 1; k < 64; k <<= 1) s += __shfl_xor(s, k, 64);
    if (lane == 0) rs[w] = s;
    __syncthreads();
    s = rs[0] + rs[1] + rs[2] + rs[3];
    float inv = 1.f / s;
#pragma unroll
    for (int i = 0; i < 8; i++) attn[(b << 11) + t + (i << 8)] = v[i] * inv;
}

__global__ void context_f32(const float* __restrict__ enc, const float* __restrict__ attn,
                            float* __restrict__ ctx) {
    int dchunk = blockIdx.x, b = blockIdx.y;
    int t = threadIdx.x;
    __shared__ __align__(16) float at_s[2048];
    __shared__ float red[16][128];
    *(float4*)&at_s[t * 4] = *(const float4*)&attn[(b << 11) + t * 4];
    __syncthreads();
    int d4 = (t & 31) << 2;
    int dl = t >> 5;
    int d0 = dchunk << 7;
    const float* base = enc + ((size_t)b << 21) + d0 + d4;
    float ax = 0.f, ay = 0.f, az = 0.f, aw = 0.f;
#pragma unroll 4
    for (int i = 0; i < 128; i++) {
        int l = (i << 4) + dl;
        float wg = at_s[l];
        float4 e = *(const float4*)(base + ((size_t)l << 10));
        ax += wg * e.x; ay += wg * e.y; az += wg * e.z; aw += wg * e.w;
    }
    red[dl][d4 + 0] = ax;
    red[dl][d4 + 1] = ay;
    red[dl][d4 + 2] = az;
    red[dl][d4 + 3] = aw;
    __syncthreads();
    if (t < 128) {
        float s = 0.f;
#pragma unroll
        for (int j = 0; j < 16; j++) s += red[j][t];
        ctx[(b << 10) + d0 + t] = s;
    }
}

extern "C" void kernel_launch(void* const* d_in, const int* in_sizes, int n_in,
                              void* d_out, int out_size, void* d_ws, size_t ws_size,
                              hipStream_t stream) {
    const float* dh  = (const float*)d_in[0];
    const float* enc = (const float*)d_in[1];
    const float* Ww  = (const float*)d_in[2];
    const float* Wb  = (const float*)d_in[3];
    const float* Uw  = (const float*)d_in[4];
    const float* Ub  = (const float*)d_in[5];
    const float* vw  = (const float*)d_in[6];
    // d_in[7] = v_b: dropped (softmax shift-invariance)

    float* out  = (float*)d_out;               // [0,32768) context, [32768,98304) attn
    float* attn = out + BB * DD;
    char*  ws   = (char*)d_ws;
    short* Ubf   = (short*)ws;                           // 2 MB
    float* qbuf  = (float*)(ws + (2 << 20));             // 128 KB
    float* sbuf  = (float*)(ws + (2 << 20) + (1 << 17)); // 1 MB (4 slabs) / 256 KB (B)
    short* encbf = (short*)(ws + (8 << 20));             // 134.2 MB (Path A)

    bool bigws = ws_size >= ((size_t)143 << 20);

    if (bigws) {
        hipMemsetAsync(out, 0, (size_t)BB * DD * sizeof(float), stream);  // zero ctx for atomics
        prep_kernel<<<33792, 256, 0, stream>>>(dh, Ww, Wb, Ub, Uw, enc, qbuf, Ubf, encbf);
        gemm_scores_bf<<<dim3(4, 256), 512, 0, stream>>>(encbf, Ubf, qbuf, vw, sbuf);
        softmax8_kernel<<<BB, 256, 0, stream>>>(sbuf, attn);
        ctx_part<<<dim3(8, 8, BB), 256, 0, stream>>>(encbf, attn, out);
    } else {
        hipMemsetAsync(sbuf, 0, (size_t)BB * LL * sizeof(float), stream);
        cvt_bf16_kernel<<<512, 256, 0, stream>>>(Uw, Ubf);
        q_kernel<<<512, 256, 0, stream>>>(dh, Ww, Wb, Ub, qbuf);
        gemm_scores_f32<<<dim3(8, 512), 256, 0, stream>>>(enc, Ubf, qbuf, vw, sbuf);
        softmax_kernel<<<BB, 256, 0, stream>>>(sbuf, attn);
        context_f32<<<dim3(8, BB), 512, 0, stream>>>(enc, attn, out);
    }
}